// Round 5
// baseline (57.446 us; speedup 1.0000x reference)
//
#include <hip/hip_runtime.h>
#include <math.h>

#define NFEAT 22
#define ROWS_PER_THREAD 2
#define BLOCK 256

// Reference quirk replicated exactly: start_i is NEVER incremented in the
// Python reference, so every node i computes relu(x[:, 0:fn_i] @ kernels[off..] + b_i).
// Only x columns 0..12 are ever read (max feature = 13) -> first 64-B sector
// of each 512-B row. R3 diag: fetch is already minimal (64 B/row), pattern
// sustains 3.57 TB/s steady-state; R4 coop-staging regressed (not TA-bound).
//
// R5 change (last lever): nontemporal loads/stores (nt flag -> no L1/L2/L3
// allocation; data has zero reuse) + branchless exact-divisible grid +
// both rows' loads issued back-to-back for max per-thread MLP.

typedef float f4 __attribute__((ext_vector_type(4)));

__global__ __launch_bounds__(BLOCK, 8) void hnn_fused_kernel(
    const float* __restrict__ x,
    const float* __restrict__ kernels,
    const float* __restrict__ biases,
    const float* __restrict__ final_kernel,
    const float* __restrict__ final_bias,
    float* __restrict__ out)
{
    constexpr int FN[NFEAT] = {10,13,13,7,3,6,3,13,5,4,6,4,5,4,4,5,4,3,3,7,3,3};

    const int base = blockIdx.x * (BLOCK * ROWS_PER_THREAD) + threadIdx.x;

    // ---- Issue all 8 load instructions for both rows up front ----
    f4 q[ROWS_PER_THREAD][3];
    float last[ROWS_PER_THREAD];
    #pragma unroll
    for (int r = 0; r < ROWS_PER_THREAD; ++r) {
        const size_t rb = (size_t)(base + r * BLOCK) * 128;
        const f4* xr = reinterpret_cast<const f4*>(x + rb);
        q[r][0] = __builtin_nontemporal_load(xr + 0);
        q[r][1] = __builtin_nontemporal_load(xr + 1);
        q[r][2] = __builtin_nontemporal_load(xr + 2);
        last[r] = __builtin_nontemporal_load(x + rb + 12);
    }

    #pragma unroll
    for (int r = 0; r < ROWS_PER_THREAD; ++r) {
        const float xv[13] = {q[r][0].x, q[r][0].y, q[r][0].z, q[r][0].w,
                              q[r][1].x, q[r][1].y, q[r][1].z, q[r][1].w,
                              q[r][2].x, q[r][2].y, q[r][2].z, q[r][2].w,
                              last[r]};

        float z = final_bias[0];
        int off = 0;
        #pragma unroll
        for (int i = 0; i < NFEAT; ++i) {
            float acc = biases[i];
            #pragma unroll
            for (int j = 0; j < FN[i]; ++j) {
                acc = fmaf(xv[j], kernels[off + j], acc);   // uniform -> s_load, ~free
            }
            off += FN[i];
            z = fmaf(fmaxf(acc, 0.0f), final_kernel[i], z);
        }

        const float s = 1.0f / (1.0f + __expf(-z));
        __builtin_nontemporal_store(s, out + base + r * BLOCK);
    }
}

extern "C" void kernel_launch(void* const* d_in, const int* in_sizes, int n_in,
                              void* d_out, int out_size, void* d_ws, size_t ws_size,
                              hipStream_t stream)
{
    const float* x            = (const float*)d_in[0];
    const float* kernels      = (const float*)d_in[1];
    const float* biases       = (const float*)d_in[2];
    const float* final_kernel = (const float*)d_in[3];
    const float* final_bias   = (const float*)d_in[4];
    float* out = (float*)d_out;

    const int batch = out_size;  // 1048576 = 2048 * 512, exact
    const int rows_per_block = BLOCK * ROWS_PER_THREAD;
    const int grid = batch / rows_per_block;  // 2048

    hnn_fused_kernel<<<grid, BLOCK, 0, stream>>>(
        x, kernels, biases, final_kernel, final_bias, out);
}

// Round 6
// 40.964 us; speedup vs baseline: 1.4023x; 1.4023x over previous
//
#include <hip/hip_runtime.h>
#include <math.h>

#define NFEAT 22
#define ROWS_PER_THREAD 4
#define BLOCK 256

// FINAL-CANDIDATE (revert to R1 structure, best measured: 25.9 us).
//
// Reference quirk replicated exactly: start_i is NEVER incremented in the
// Python reference, so every node i computes relu(x[:, 0:fn_i] @ kernels[off..] + b_i).
// Only x columns 0..12 are ever read (max feature = 13) -> first 64-B sector
// of each 512-B row.
//
// Evidence ledger (R2-R5): fetch already minimal at 64 B/row (R3 diag);
// 2x occupancy null (R2); LDS-coalesced staging regressed (R4); nontemporal
// regressed 2.2x (R5). Pattern sustains ~3.57 TB/s steady-state (R3) ->
// single-shot floor ~18 us data + ramp/tail = the ~26 us we measure.
// Bound by DRAM efficiency on sparse 64B/512B stream; not source-addressable.

__global__ __launch_bounds__(BLOCK) void hnn_fused_kernel(
    const float* __restrict__ x,
    const float* __restrict__ kernels,
    const float* __restrict__ biases,
    const float* __restrict__ final_kernel,
    const float* __restrict__ final_bias,
    float* __restrict__ out)
{
    constexpr int FN[NFEAT] = {10,13,13,7,3,6,3,13,5,4,6,4,5,4,4,5,4,3,3,7,3,3};

    const int base = blockIdx.x * (BLOCK * ROWS_PER_THREAD) + threadIdx.x;

    #pragma unroll
    for (int r = 0; r < ROWS_PER_THREAD; ++r) {
        const int row = base + r * BLOCK;   // batch divides grid exactly: no bounds check

        const size_t rb = (size_t)row * 128;
        const float4* xr = reinterpret_cast<const float4*>(x + rb);

        // Load the 13 live columns: 3 x float4 (floats 0..11) + 1 scalar (float 12).
        float4 a = xr[0];
        float4 b = xr[1];
        float4 c = xr[2];
        float xv[13] = {a.x, a.y, a.z, a.w,
                        b.x, b.y, b.z, b.w,
                        c.x, c.y, c.z, c.w,
                        x[rb + 12]};

        float z = final_bias[0];
        int off = 0;
        #pragma unroll
        for (int i = 0; i < NFEAT; ++i) {
            float acc = biases[i];
            #pragma unroll
            for (int j = 0; j < FN[i]; ++j) {
                acc = fmaf(xv[j], kernels[off + j], acc);   // uniform -> s_load, ~free
            }
            off += FN[i];
            z = fmaf(fmaxf(acc, 0.0f), final_kernel[i], z);
        }

        out[row] = 1.0f / (1.0f + __expf(-z));
    }
}

extern "C" void kernel_launch(void* const* d_in, const int* in_sizes, int n_in,
                              void* d_out, int out_size, void* d_ws, size_t ws_size,
                              hipStream_t stream)
{
    const float* x            = (const float*)d_in[0];
    const float* kernels      = (const float*)d_in[1];
    const float* biases       = (const float*)d_in[2];
    const float* final_kernel = (const float*)d_in[3];
    const float* final_bias   = (const float*)d_in[4];
    float* out = (float*)d_out;

    const int batch = out_size;  // 1048576 = 1024 * 1024, divides exactly
    const int rows_per_block = BLOCK * ROWS_PER_THREAD;
    const int grid = batch / rows_per_block;  // 1024

    hnn_fused_kernel<<<grid, BLOCK, 0, stream>>>(
        x, kernels, biases, final_kernel, final_bias, out);
}

// Round 7
// 26.532 us; speedup vs baseline: 2.1652x; 1.5439x over previous
//
#include <hip/hip_runtime.h>
#include <math.h>

#define NFEAT 22
#define ROWS_PER_THREAD 4
#define BLOCK 256

// FINAL-CANDIDATE: byte-exact re-bench of R1 (best measured: 25.88 us).
// R6 lesson: removing the per-row bounds branch regressed 26->41 us — the
// branch keeps the compiler's per-row [load->compute->store] grouping; without
// it, 16 loads hoist into one burst + 4 sunk stores. Keep the branch.
//
// Reference quirk replicated exactly: start_i is NEVER incremented in the
// Python reference, so every node i computes relu(x[:, 0:fn_i] @ kernels[off..] + b_i).
// Only x columns 0..12 are ever read (max feature = 13) -> first 64-B sector
// of each 512-B row.
//
// Evidence ledger (R2-R6): fetch already minimal at 64 B/row (R3 diag);
// 2x occupancy null (R2); LDS-coalesced staging regressed (R4); nontemporal
// regressed 2.2x (R5); branchless/hoisted-loads regressed (R6). Pattern
// sustains ~3.57 TB/s steady-state (R3) -> single-shot floor ~19 us data +
// ramp/tail = ~26 us. DRAM-pattern-bound; not further source-addressable.

__global__ __launch_bounds__(BLOCK) void hnn_fused_kernel(
    const float* __restrict__ x,
    const float* __restrict__ kernels,
    const float* __restrict__ biases,
    const float* __restrict__ final_kernel,
    const float* __restrict__ final_bias,
    float* __restrict__ out,
    int batch)
{
    constexpr int FN[NFEAT] = {10,13,13,7,3,6,3,13,5,4,6,4,5,4,4,5,4,3,3,7,3,3};

    const int base = blockIdx.x * (BLOCK * ROWS_PER_THREAD) + threadIdx.x;

    #pragma unroll
    for (int r = 0; r < ROWS_PER_THREAD; ++r) {
        const int row = base + r * BLOCK;
        if (row >= batch) continue;

        const size_t rb = (size_t)row * 128;
        const float4* xr = reinterpret_cast<const float4*>(x + rb);

        // Load the 13 live columns: 3 x float4 (floats 0..11) + 1 scalar (float 12).
        float4 a = xr[0];
        float4 b = xr[1];
        float4 c = xr[2];
        float xv[13] = {a.x, a.y, a.z, a.w,
                        b.x, b.y, b.z, b.w,
                        c.x, c.y, c.z, c.w,
                        x[rb + 12]};

        float z = final_bias[0];
        int off = 0;
        #pragma unroll
        for (int i = 0; i < NFEAT; ++i) {
            float acc = biases[i];
            #pragma unroll
            for (int j = 0; j < FN[i]; ++j) {
                acc = fmaf(xv[j], kernels[off + j], acc);   // compile-time offsets -> scalar loads
            }
            off += FN[i];
            z = fmaf(fmaxf(acc, 0.0f), final_kernel[i], z);
        }

        // sigmoid
        out[row] = 1.0f / (1.0f + __expf(-z));
    }
}

extern "C" void kernel_launch(void* const* d_in, const int* in_sizes, int n_in,
                              void* d_out, int out_size, void* d_ws, size_t ws_size,
                              hipStream_t stream)
{
    const float* x            = (const float*)d_in[0];
    const float* kernels      = (const float*)d_in[1];
    const float* biases       = (const float*)d_in[2];
    const float* final_kernel = (const float*)d_in[3];
    const float* final_bias   = (const float*)d_in[4];
    float* out = (float*)d_out;

    const int batch = out_size;  // 1048576
    const int rows_per_block = BLOCK * ROWS_PER_THREAD;
    const int grid = (batch + rows_per_block - 1) / rows_per_block;

    hnn_fused_kernel<<<grid, BLOCK, 0, stream>>>(
        x, kernels, biases, final_kernel, final_bias, out, batch);
}